// Round 4
// baseline (201.980 us; speedup 1.0000x reference)
//
#include <hip/hip_runtime.h>

#define Lq 512
#define Bn 1024
#define Tq 48

// ---------------- Forward algorithm (log partition function) ----------------
// One wave per batch element (1024 blocks x 64 threads = 1 wave/SIMD).
// Lane j holds P[j] (fp32, linear domain) and W column j in registers.
// Per-step broadcast of P goes through LDS same-address reads (DS pipe,
// co-issues with VALU) instead of v_readlane (VALU->SGPR hazard stalls).
// Rescale by lane-0's power-of-2 exponent every 4 steps (exact, 1 VALU op).
__global__ __launch_bounds__(64) void crf_forward(
    const float* __restrict__ em, const int* __restrict__ mask,
    const float* __restrict__ startT, const float* __restrict__ endT,
    const float* __restrict__ trans, float* __restrict__ out)
{
    const int j  = threadIdx.x;       // 0..63
    const int b  = blockIdx.x;        // wave-uniform
    const int jc = j < Tq ? j : Tq - 1;
    const bool act = j < Tq;

    __shared__ float sh[64] __attribute__((aligned(16)));

    // W column j: w[i] = exp(trans[i][j]); zero for inactive lanes keeps p=0
    float w[Tq];
#pragma unroll
    for (int i = 0; i < Tq; ++i) {
        float wv = __expf(trans[i * Tq + jc]);
        w[i] = act ? wv : 0.0f;
    }

    float p = act ? __expf(startT[jc] + em[(size_t)b * Tq + jc]) : 0.0f;
    int c2 = 0;   // sum of removed power-of-2 exponents (exact)

    const int U = 8;
    float eb[U]; int mb[U]; float ex[U];
#pragma unroll
    for (int u = 0; u < U; ++u) {
        int t = 1 + u;
        eb[u] = em[((size_t)t * Bn + b) * Tq + jc];
        mb[u] = mask[t * Bn + b];
    }

    // one matvec step: p_j = (sum_i P[i]*w[i][j]) * exp(e_j)
    auto step = [&](float expe) {
        sh[j] = p;                       // same-wave LDS: in-order DS pipe
        float a0 = 0.f, a1 = 0.f, a2 = 0.f, a3 = 0.f;
#pragma unroll
        for (int i = 0; i < Tq; i += 4) {  // consecutive -> ds_read_b128 merge
            a0 = fmaf(sh[i + 0], w[i + 0], a0);
            a1 = fmaf(sh[i + 1], w[i + 1], a1);
            a2 = fmaf(sh[i + 2], w[i + 2], a2);
            a3 = fmaf(sh[i + 3], w[i + 3], a3);
        }
        float s = (a0 + a1) + (a2 + a3);
        p = s * expe;
    };

    // exact power-of-2 rescale from lane 0's exponent (no cross-lane chain)
    auto rescale = [&]() {
        int pb = __builtin_amdgcn_readlane(__float_as_int(p), 0);
        int k  = (pb >> 23) - 126;                 // frexp-style exponent
        float scl = __int_as_float((127 - k) << 23);  // 2^-k, exact
        p *= scl;
        c2 += k;
    };

    for (int g = 0; g < (Lq - 1 + U - 1) / U; ++g) {
        // prefetch next group (8 steps ahead >> HBM latency)
        float en[U]; int mn[U];
        const int tn = 1 + (g + 1) * U;
#pragma unroll
        for (int u = 0; u < U; ++u) {
            int t  = tn + u;
            int tc = t < Lq ? t : Lq - 1;
            en[u] = em[((size_t)tc * Bn + b) * Tq + jc];
            mn[u] = t < Lq ? mask[tc * Bn + b] : 0;
        }
        // hoist exp(e) off the critical path (independent of p)
#pragma unroll
        for (int u = 0; u < U; ++u) ex[u] = __expf(eb[u]);

        int allm = __builtin_amdgcn_readfirstlane(
            mb[0] & mb[1] & mb[2] & mb[3] & mb[4] & mb[5] & mb[6] & mb[7]);
        if (allm) {                        // common case: straight-line 8 steps
#pragma unroll
            for (int u = 0; u < U; ++u) {
                step(ex[u]);
                if ((u & 3) == 3) rescale();
            }
        } else {                           // tail: per-step uniform branch
#pragma unroll
            for (int u = 0; u < U; ++u) {
                if (__builtin_amdgcn_readfirstlane(mb[u])) step(ex[u]);
                if ((u & 3) == 3) rescale();
            }
        }
#pragma unroll
        for (int u = 0; u < U; ++u) { eb[u] = en[u]; mb[u] = mn[u]; }
    }

    // log_z = ln(sum_j P[j]*exp(end[j])) + c2*ln2 ; accumulate -log_z
    float ez = act ? __expf(endT[jc]) : 0.0f;
    float z = p * ez;
#pragma unroll
    for (int off = 32; off >= 1; off >>= 1)
        z += __shfl_xor(z, off, 64);
    if (j == 0) {
        double lz = (double)__logf(z) + (double)c2 * 0.6931471805599453;
        atomicAdd(out, (float)(-lz));
    }
}

// ---------------- Numerator (gold-path score) ----------------
// One thread per (t,b); block-reduce -> 1 atomic per block.
__global__ __launch_bounds__(256) void crf_llh(
    const float* __restrict__ em, const int* __restrict__ tags,
    const int* __restrict__ mask, const float* __restrict__ startT,
    const float* __restrict__ endT, const float* __restrict__ trans,
    float* __restrict__ out)
{
    int id = blockIdx.x * blockDim.x + threadIdx.x;   // id = t*Bn + b
    float c = 0.0f;
    {
        int t  = id >> 10;          // / Bn (Bn = 1024)
        int bb = id & (Bn - 1);
        int tag = tags[id];
        int m_t = mask[id];
        if (t == 0) c += startT[tag];
        bool is_last;
        if (t < Lq - 1) {
            if (m_t) c += em[(size_t)id * Tq + tag];     // emis*mask[:-1]
            int tag1 = tags[id + Bn];
            int m1   = mask[id + Bn];
            if (m1) c += trans[tag * Tq + tag1];         // trans*mask[1:]
            is_last = (m_t != 0) && (m1 == 0);
        } else {
            is_last = (m_t != 0);
        }
        if (is_last) {
            c += endT[tag];
            int mL = mask[(Lq - 1) * Bn + bb];
            if (mL) c += em[((size_t)(Lq - 1) * Bn + bb) * Tq + tag];
        }
    }
#pragma unroll
    for (int off = 32; off >= 1; off >>= 1)
        c += __shfl_xor(c, off, 64);
    __shared__ float red[4];
    if ((threadIdx.x & 63) == 0) red[threadIdx.x >> 6] = c;
    __syncthreads();
    if (threadIdx.x == 0)
        atomicAdd(out, red[0] + red[1] + red[2] + red[3]);
}

extern "C" void kernel_launch(void* const* d_in, const int* in_sizes, int n_in,
                              void* d_out, int out_size, void* d_ws, size_t ws_size,
                              hipStream_t stream) {
    const float* em     = (const float*)d_in[0];
    const int*   tags   = (const int*)d_in[1];
    const int*   mask   = (const int*)d_in[2];
    const float* startT = (const float*)d_in[3];
    const float* endT   = (const float*)d_in[4];
    const float* trans  = (const float*)d_in[5];
    float* out = (float*)d_out;

    hipMemsetAsync(out, 0, sizeof(float), stream);
    crf_llh<<<(Lq * Bn) / 256, 256, 0, stream>>>(em, tags, mask, startT, endT, trans, out);
    crf_forward<<<Bn, 64, 0, stream>>>(em, mask, startT, endT, trans, out);
}